// Round 1
// baseline (423.525 us; speedup 1.0000x reference)
//
#include <hip/hip_runtime.h>

// Row-wise L1 normalization: x[bs, r, d] -> x * 1/max(rowsum, EPS)
// bs=16, r=2048, d=2048, fp32. One 256-thread block per row; each thread
// holds 8 floats (2x float4) in registers across reduce + scale so input
// is read from HBM exactly once.

#define ROW_LEN 2048
#define BLOCK   256

__global__ __launch_bounds__(BLOCK) void rownorm_kernel(
    const float* __restrict__ in, float* __restrict__ out) {
    const int row = blockIdx.x;                 // 0 .. 32767
    const size_t base = (size_t)row * ROW_LEN;  // row start (float4-aligned)
    const float4* __restrict__ in4 = (const float4*)(in + base);
    float4* __restrict__ out4 = (float4*)(out + base);

    const int t = threadIdx.x;

    // Each thread: 2 float4 loads = 8 floats; 256 threads cover 2048 exactly.
    float4 a = in4[t];
    float4 b = in4[t + BLOCK];

    float s = (a.x + a.y) + (a.z + a.w) + (b.x + b.y) + (b.z + b.w);

    // 64-lane wave shuffle reduction.
    #pragma unroll
    for (int off = 32; off > 0; off >>= 1)
        s += __shfl_down(s, off, 64);

    __shared__ float wsum[BLOCK / 64];
    __shared__ float inv_s;
    const int lane = t & 63;
    const int wid  = t >> 6;
    if (lane == 0) wsum[wid] = s;
    __syncthreads();
    if (t == 0) {
        float tot = (wsum[0] + wsum[1]) + (wsum[2] + wsum[3]);
        inv_s = 1.0f / fmaxf(tot, 1e-5f);
    }
    __syncthreads();
    const float inv = inv_s;

    a.x *= inv; a.y *= inv; a.z *= inv; a.w *= inv;
    b.x *= inv; b.y *= inv; b.z *= inv; b.w *= inv;
    out4[t]         = a;
    out4[t + BLOCK] = b;
}

extern "C" void kernel_launch(void* const* d_in, const int* in_sizes, int n_in,
                              void* d_out, int out_size, void* d_ws, size_t ws_size,
                              hipStream_t stream) {
    const float* in = (const float*)d_in[0];
    float* out = (float*)d_out;
    const int n_rows = in_sizes[0] / ROW_LEN;   // 16 * 2048 = 32768
    rownorm_kernel<<<n_rows, BLOCK, 0, stream>>>(in, out);
}